// Round 3
// baseline (802.168 us; speedup 1.0000x reference)
//
#include <hip/hip_runtime.h>

#define NN 16
#define CIN 256
#define COUT 256
#define LL 300
#define VV 25
#define VP 28                  // padded Aw row (112 B, 16B-aligned)
#define PP 3
#define KS 9
#define KK 768                 // GEMM K = P*CIN
#define MM (NN*LL*VV)          // 120000 GEMM rows
#define MPAD 120064            // 938 * 128
#define MBLK 938
#define TM 10                  // m-chunk per k1 block

typedef float floatx4 __attribute__((ext_vector_type(4)));
typedef short short8 __attribute__((ext_vector_type(8)));

__device__ __forceinline__ unsigned short f2bf(float f) {
    unsigned u = __builtin_bit_cast(unsigned, f);
    u += 0x7fff + ((u >> 16) & 1);          // round-to-nearest-even
    return (unsigned short)(u >> 16);
}
__device__ __forceinline__ float bf2f(unsigned short h) {
    unsigned u = ((unsigned)h) << 16;
    return __builtin_bit_cast(float, u);
}
__device__ __forceinline__ void gl2lds16(const void* g, void* l) {
    __builtin_amdgcn_global_load_lds(
        (const __attribute__((address_space(1))) void*)g,
        (__attribute__((address_space(3))) void*)l, 16, 0, 0);
}

// ---------------- prep: W2T (bf16, N x K), bias2[c][w], zero xa pad rows ----
__global__ __launch_bounds__(256) void k_prep(
    const float* __restrict__ A, const float* __restrict__ conv_w,
    const float* __restrict__ conv_b, const float* __restrict__ ei,
    unsigned short* __restrict__ w2t, float* __restrict__ bias2,
    unsigned short* __restrict__ xa)
{
    const int t = blockIdx.x * 256 + threadIdx.x;
    const int nthr = gridDim.x * 256;
    for (int idx = t; idx < COUT * KK; idx += nthr) {
        int c = idx / KK, k = idx % KK, p = k >> 8, ci = k & 255;
        w2t[idx] = f2bf(conv_w[(p * COUT + c) * CIN + ci]);
    }
    for (int idx = t; idx < COUT * VV; idx += nthr) {
        int c = idx / VV, w = idx % VV;
        float s = 0.f;
        for (int p = 0; p < PP; ++p) {
            float cs = 0.f;
            for (int v = 0; v < VV; ++v) {
                int a = (p * VV + v) * VV + w;
                cs += A[a] * ei[a];
            }
            s += conv_b[p * COUT + c] * cs;
        }
        bias2[idx] = s;
    }
    for (int idx = t; idx < (MPAD - MM) * KK; idx += nthr)
        xa[(size_t)MM * KK + idx] = 0;
}

// ---- k1: sliding 9-tap temporal sum on x + graph aggregation + transpose ---
// xa[(n,m,w)][(p,ci)] = sum_v ( sum_{l in win(m)} x[n,ci,l,v] ) * Aw[p,v,w]
__global__ __launch_bounds__(256) void k1_temporal_agg(
    const float* __restrict__ x, const float* __restrict__ A,
    const float* __restrict__ ei, unsigned short* __restrict__ xa)
{
    __shared__ float AwL[PP * VV * VP];   // [p][v][w], rows padded to 28
    const int n = blockIdx.y, t = threadIdx.x;          // t = ci
    const int m0 = blockIdx.x * TM;

    for (int idx = t; idx < PP * VV * VV; idx += 256) {
        int pv = idx / VV, w = idx % VV;
        AwL[pv * VP + w] = A[idx] * ei[idx];
    }
    __syncthreads();

    const float* xbase = x + (size_t)(n * CIN + t) * LL * VV;

    // warm-up window for m0: l in [max(0,m0-8), m0]
    float wsum[VV];
    #pragma unroll
    for (int v = 0; v < VV; ++v) wsum[v] = 0.f;
    const int lw0 = (m0 >= KS - 1) ? (m0 - (KS - 1)) : 0;
    for (int l = lw0; l <= m0; ++l) {
        const float* xp = xbase + l * VV;
        #pragma unroll
        for (int v = 0; v < VV; ++v) wsum[v] += xp[v];
    }

    for (int m = m0; m < m0 + TM; ++m) {
        if (m > m0) {
            const float* xp = xbase + m * VV;
            #pragma unroll
            for (int v = 0; v < VV; ++v) wsum[v] += xp[v];
            if (m - KS >= 0) {
                const float* xo = xbase + (m - KS) * VV;
                #pragma unroll
                for (int v = 0; v < VV; ++v) wsum[v] -= xo[v];
            }
        }
        const size_t mrow = (size_t)(n * LL + m) * VV;
        #pragma unroll
        for (int p = 0; p < PP; ++p) {
            float acc[VV];
            #pragma unroll
            for (int w = 0; w < VV; ++w) acc[w] = 0.f;
            #pragma unroll
            for (int v = 0; v < VV; ++v) {
                const float xvv = wsum[v];
                const float* ar = &AwL[(p * VV + v) * VP];
                #pragma unroll
                for (int wq = 0; wq < 24; wq += 4) {
                    const float4 f = *(const float4*)(ar + wq);
                    acc[wq + 0] += xvv * f.x; acc[wq + 1] += xvv * f.y;
                    acc[wq + 2] += xvv * f.z; acc[wq + 3] += xvv * f.w;
                }
                acc[24] += xvv * ar[24];
            }
            #pragma unroll
            for (int w = 0; w < VV; ++w)
                xa[(mrow + w) * KK + p * CIN + t] = f2bf(acc[w]);
        }
    }
}

// ---------------- GEMM: z[m][c] = xa[m][:] . w2t[c][:]  (bf16 MFMA) --------
__global__ __launch_bounds__(256) void k_gemm(
    const unsigned short* __restrict__ xa,
    const unsigned short* __restrict__ w2t,
    unsigned short* __restrict__ z)
{
    __shared__ __align__(16) unsigned short As[128 * 32];
    __shared__ __align__(16) unsigned short Bs[128 * 32];
    const int t = threadIdx.x, wv = t >> 6, ln = t & 63;
    const int m0 = blockIdx.x * 128, c0 = blockIdx.y * 128;

    floatx4 acc[4][4];
    #pragma unroll
    for (int i = 0; i < 4; ++i)
        #pragma unroll
        for (int j = 0; j < 4; ++j)
            acc[i][j] = (floatx4){0.f, 0.f, 0.f, 0.f};

    const int srow = wv * 32 + (ln >> 2);
    const int scol = (ln & 3) * 8;
    const int mw = (wv >> 1) * 64, nw = (wv & 1) * 64;
    const int frow = ln & 15, fcol = (ln >> 4) * 8;

    for (int kt = 0; kt < KK / 32; ++kt) {
        const int k0 = kt * 32;
        __syncthreads();
        gl2lds16(xa  + (size_t)(m0 + srow)      * KK + k0 + scol, &As[(wv * 32) * 32]);
        gl2lds16(xa  + (size_t)(m0 + srow + 16) * KK + k0 + scol, &As[(wv * 32 + 16) * 32]);
        gl2lds16(w2t + (size_t)(c0 + srow)      * KK + k0 + scol, &Bs[(wv * 32) * 32]);
        gl2lds16(w2t + (size_t)(c0 + srow + 16) * KK + k0 + scol, &Bs[(wv * 32 + 16) * 32]);
        __syncthreads();

        short8 af[4], bf[4];
        #pragma unroll
        for (int i = 0; i < 4; ++i)
            af[i] = *(const short8*)&As[(mw + i * 16 + frow) * 32 + fcol];
        #pragma unroll
        for (int j = 0; j < 4; ++j)
            bf[j] = *(const short8*)&Bs[(nw + j * 16 + frow) * 32 + fcol];
        #pragma unroll
        for (int i = 0; i < 4; ++i)
            #pragma unroll
            for (int j = 0; j < 4; ++j)
                acc[i][j] = __builtin_amdgcn_mfma_f32_16x16x32_bf16(af[i], bf[j], acc[i][j], 0, 0, 0);
    }

    const int q = ln >> 4, cL = ln & 15;
    #pragma unroll
    for (int i = 0; i < 4; ++i) {
        #pragma unroll
        for (int j = 0; j < 4; ++j) {
            #pragma unroll
            for (int r = 0; r < 4; ++r) {
                const int m = m0 + mw + i * 16 + q * 4 + r;
                const int c = c0 + nw + j * 16 + cL;
                if (m < MM) z[(size_t)m * COUT + c] = f2bf(acc[i][j][r]);
            }
        }
    }
}

// ---------------- bias + LayerNorm + relu + residual + relu ----------------
__global__ __launch_bounds__(256) void k_ln(
    const unsigned short* __restrict__ z, const float* __restrict__ x,
    const float* __restrict__ bias2, const float* __restrict__ gamma,
    const float* __restrict__ beta, float* __restrict__ out)
{
    const int m = blockIdx.x, n = blockIdx.y, t = threadIdx.x;  // t = c
    const int l0 = (m >= KS - 1) ? (m - (KS - 1)) : 0;
    const float cnt = (float)(m - l0 + 1);

    float zw[VV];
    const unsigned short* zp = z + (size_t)((n * LL + m) * VV) * COUT + t;
    const float* b2 = bias2 + t * VV;
    #pragma unroll
    for (int w = 0; w < VV; ++w)
        zw[w] = bf2f(zp[(size_t)w * COUT]) + cnt * b2[w];

    float s1 = 0.f, s2 = 0.f;
    #pragma unroll
    for (int w = 0; w < VV; ++w) { s1 += zw[w]; s2 += zw[w] * zw[w]; }

    __shared__ float rs[4], rq[4], stats[2];
    #pragma unroll
    for (int off = 32; off; off >>= 1) { s1 += __shfl_down(s1, off); s2 += __shfl_down(s2, off); }
    const int wid = t >> 6, lane = t & 63;
    if (lane == 0) { rs[wid] = s1; rq[wid] = s2; }
    __syncthreads();
    if (t == 0) {
        const float S1 = rs[0] + rs[1] + rs[2] + rs[3];
        const float S2 = rq[0] + rq[1] + rq[2] + rq[3];
        const float inv = 1.f / (COUT * VV);
        const float mu = S1 * inv;
        const float var = S2 * inv - mu * mu;
        stats[0] = mu;
        stats[1] = rsqrtf(var + 1e-5f);
    }
    __syncthreads();
    const float mu = stats[0], rsd = stats[1];

    const float* gp = gamma + t * VV;
    const float* bp = beta + t * VV;
    const float* xp = x + ((size_t)(n * CIN + t) * LL + m) * VV;
    float* op = out + ((size_t)(n * COUT + t) * LL + m) * VV;
    #pragma unroll
    for (int w = 0; w < VV; ++w) {
        float val = (zw[w] - mu) * rsd * gp[w] + bp[w];
        val = fmaxf(val, 0.f);
        val += xp[w];
        op[w] = fmaxf(val, 0.f);
    }
}

extern "C" void kernel_launch(void* const* d_in, const int* in_sizes, int n_in,
                              void* d_out, int out_size, void* d_ws, size_t ws_size,
                              hipStream_t stream) {
    const float* x      = (const float*)d_in[0];
    const float* A      = (const float*)d_in[1];
    const float* conv_w = (const float*)d_in[2];
    const float* conv_b = (const float*)d_in[3];
    const float* gamma  = (const float*)d_in[4];
    const float* beta   = (const float*)d_in[5];
    const float* ei     = (const float*)d_in[6];
    float* out = (float*)d_out;

    char* ws = (char*)d_ws;
    unsigned short* xa  = (unsigned short*)ws;                    // 184,418,304 B
    unsigned short* z   = (unsigned short*)(ws + 184418304);      //  61,472,768 B
    unsigned short* w2t = (unsigned short*)(ws + 245891072);      //     393,216 B
    float*          b2  = (float*)(ws + 246284288);               //      25,600 B

    k_prep<<<64, 256, 0, stream>>>(A, conv_w, conv_b, ei, w2t, b2, xa);
    k1_temporal_agg<<<dim3(LL / TM, NN), 256, 0, stream>>>(x, A, ei, xa);
    k_gemm<<<dim3(MBLK, 2), 256, 0, stream>>>(xa, w2t, z);
    k_ln<<<dim3(LL, NN), 256, 0, stream>>>(z, x, b2, gamma, beta, out);
}

// Round 4
// 550.482 us; speedup vs baseline: 1.4572x; 1.4572x over previous
//
#include <hip/hip_runtime.h>

#define NN 16
#define CIN 256
#define COUT 256
#define LL 300
#define VV 25
#define VP 28                  // padded Aw row (112 B, 16B-aligned)
#define PP 3
#define KS 9
#define KK 768                 // GEMM K = P*CIN
#define MM (NN*LL*VV)          // 120000 GEMM rows
#define MPAD 120064            // 938 * 128
#define MBLK 938
#define XCDS 8
#define MPX 38                 // ceil(300/8) m's per XCD-slice

typedef float floatx4 __attribute__((ext_vector_type(4)));
typedef short short8 __attribute__((ext_vector_type(8)));

__device__ __forceinline__ unsigned short f2bf(float f) {
    unsigned u = __builtin_bit_cast(unsigned, f);
    u += 0x7fff + ((u >> 16) & 1);          // round-to-nearest-even
    return (unsigned short)(u >> 16);
}
__device__ __forceinline__ float bf2f(unsigned short h) {
    unsigned u = ((unsigned)h) << 16;
    return __builtin_bit_cast(float, u);
}
__device__ __forceinline__ void gl2lds16(const void* g, void* l) {
    __builtin_amdgcn_global_load_lds(
        (const __attribute__((address_space(1))) void*)g,
        (__attribute__((address_space(3))) void*)l, 16, 0, 0);
}

// ---------------- prep: W2T (bf16, N x K), bias2[c][w], zero xa pad rows ----
__global__ __launch_bounds__(256) void k_prep(
    const float* __restrict__ A, const float* __restrict__ conv_w,
    const float* __restrict__ conv_b, const float* __restrict__ ei,
    unsigned short* __restrict__ w2t, float* __restrict__ bias2,
    unsigned short* __restrict__ xa)
{
    const int t = blockIdx.x * 256 + threadIdx.x;
    const int nthr = gridDim.x * 256;
    for (int idx = t; idx < COUT * KK; idx += nthr) {
        int c = idx / KK, k = idx % KK, p = k >> 8, ci = k & 255;
        w2t[idx] = f2bf(conv_w[(p * COUT + c) * CIN + ci]);
    }
    for (int idx = t; idx < COUT * VV; idx += nthr) {
        int c = idx / VV, w = idx % VV;
        float s = 0.f;
        for (int p = 0; p < PP; ++p) {
            float cs = 0.f;
            for (int v = 0; v < VV; ++v) {
                int a = (p * VV + v) * VV + w;
                cs += A[a] * ei[a];
            }
            s += conv_b[p * COUT + c] * cs;
        }
        bias2[idx] = s;
    }
    for (int idx = t; idx < (MPAD - MM) * KK; idx += nthr)
        xa[(size_t)MM * KK + idx] = 0;
}

// ---------------- pre-aggregation: xa[(n,l,w)][(p,ci)] = sum_v x*Aw --------
__global__ __launch_bounds__(256) void k_agg(
    const float* __restrict__ x, const float* __restrict__ A,
    const float* __restrict__ ei, unsigned short* __restrict__ xa)
{
    __shared__ float AwL[PP * VV * VP];   // [p][v][w], rows padded to 28
    const int l = blockIdx.x, n = blockIdx.y, t = threadIdx.x;  // t = ci
    for (int idx = t; idx < PP * VV * VV; idx += 256) {
        int pv = idx / VV, w = idx % VV;
        AwL[pv * VP + w] = A[idx] * ei[idx];
    }
    __syncthreads();

    float xv[VV];
    const float* xp = x + ((size_t)(n * CIN + t) * LL + l) * VV;
    #pragma unroll
    for (int v = 0; v < VV; ++v) xv[v] = xp[v];

    const size_t mrow = (size_t)(n * LL + l) * VV;
    #pragma unroll
    for (int p = 0; p < PP; ++p) {
        float acc[VV];
        #pragma unroll
        for (int w = 0; w < VV; ++w) acc[w] = 0.f;
        #pragma unroll
        for (int v = 0; v < VV; ++v) {
            const float xvv = xv[v];
            const float* ar = &AwL[(p * VV + v) * VP];
            #pragma unroll
            for (int wq = 0; wq < 24; wq += 4) {
                const float4 f = *(const float4*)(ar + wq);
                acc[wq + 0] += xvv * f.x; acc[wq + 1] += xvv * f.y;
                acc[wq + 2] += xvv * f.z; acc[wq + 3] += xvv * f.w;
            }
            acc[24] += xvv * ar[24];
        }
        #pragma unroll
        for (int w = 0; w < VV; ++w)
            xa[(mrow + w) * KK + p * CIN + t] = f2bf(acc[w]);
    }
}

// ---------------- GEMM: z[m][c] = xa[m][:] . w2t[c][:]  (bf16 MFMA) --------
__global__ __launch_bounds__(256) void k_gemm(
    const unsigned short* __restrict__ xa,
    const unsigned short* __restrict__ w2t,
    unsigned short* __restrict__ z)
{
    __shared__ __align__(16) unsigned short As[128 * 32];
    __shared__ __align__(16) unsigned short Bs[128 * 32];
    const int t = threadIdx.x, wv = t >> 6, ln = t & 63;
    const int m0 = blockIdx.x * 128, c0 = blockIdx.y * 128;

    floatx4 acc[4][4];
    #pragma unroll
    for (int i = 0; i < 4; ++i)
        #pragma unroll
        for (int j = 0; j < 4; ++j)
            acc[i][j] = (floatx4){0.f, 0.f, 0.f, 0.f};

    const int srow = wv * 32 + (ln >> 2);
    const int scol = (ln & 3) * 8;
    const int mw = (wv >> 1) * 64, nw = (wv & 1) * 64;
    const int frow = ln & 15, fcol = (ln >> 4) * 8;

    for (int kt = 0; kt < KK / 32; ++kt) {
        const int k0 = kt * 32;
        __syncthreads();
        gl2lds16(xa  + (size_t)(m0 + srow)      * KK + k0 + scol, &As[(wv * 32) * 32]);
        gl2lds16(xa  + (size_t)(m0 + srow + 16) * KK + k0 + scol, &As[(wv * 32 + 16) * 32]);
        gl2lds16(w2t + (size_t)(c0 + srow)      * KK + k0 + scol, &Bs[(wv * 32) * 32]);
        gl2lds16(w2t + (size_t)(c0 + srow + 16) * KK + k0 + scol, &Bs[(wv * 32 + 16) * 32]);
        __syncthreads();

        short8 af[4], bf[4];
        #pragma unroll
        for (int i = 0; i < 4; ++i)
            af[i] = *(const short8*)&As[(mw + i * 16 + frow) * 32 + fcol];
        #pragma unroll
        for (int j = 0; j < 4; ++j)
            bf[j] = *(const short8*)&Bs[(nw + j * 16 + frow) * 32 + fcol];
        #pragma unroll
        for (int i = 0; i < 4; ++i)
            #pragma unroll
            for (int j = 0; j < 4; ++j)
                acc[i][j] = __builtin_amdgcn_mfma_f32_16x16x32_bf16(af[i], bf[j], acc[i][j], 0, 0, 0);
    }

    const int q = ln >> 4, cL = ln & 15;
    #pragma unroll
    for (int i = 0; i < 4; ++i) {
        #pragma unroll
        for (int j = 0; j < 4; ++j) {
            #pragma unroll
            for (int r = 0; r < 4; ++r) {
                const int m = m0 + mw + i * 16 + q * 4 + r;
                const int c = c0 + nw + j * 16 + cL;
                if (m < MM) z[(size_t)m * COUT + c] = f2bf(acc[i][j][r]);
            }
        }
    }
}

// ------- 9-tap temporal sum + bias + LayerNorm + relu + residual + relu ----
// XCD-locality swizzle: bid = g + 8*(mi + 38*n); XCD g owns m in [g*38, g*38+37].
// A z-row's 9 consumers run back-to-back on one XCD -> window stays L2-hot.
__global__ __launch_bounds__(256) void k_ln(
    const unsigned short* __restrict__ z, const float* __restrict__ x,
    const float* __restrict__ bias2, const float* __restrict__ gamma,
    const float* __restrict__ beta, float* __restrict__ out)
{
    const int b = blockIdx.x;
    const int g = b & (XCDS - 1);
    const int r = b >> 3;
    const int mi = r % MPX;
    const int n = r / MPX;
    const int m = g * MPX + mi;
    if (m >= LL) return;
    const int t = threadIdx.x;                       // t = c

    float zw[VV];
    #pragma unroll
    for (int w = 0; w < VV; ++w) zw[w] = 0.f;

    const int l0 = (m >= KS - 1) ? (m - (KS - 1)) : 0;
    for (int l = l0; l <= m; ++l) {
        const unsigned short* zp = z + (size_t)((n * LL + l) * VV) * COUT + t;
        #pragma unroll
        for (int w = 0; w < VV; ++w) zw[w] += bf2f(zp[(size_t)w * COUT]);
    }
    const float cnt = (float)(m - l0 + 1);
    const float* b2 = bias2 + t * VV;
    #pragma unroll
    for (int w = 0; w < VV; ++w) zw[w] += cnt * b2[w];

    float s1 = 0.f, s2 = 0.f;
    #pragma unroll
    for (int w = 0; w < VV; ++w) { s1 += zw[w]; s2 += zw[w] * zw[w]; }

    __shared__ float rs[4], rq[4], stats[2];
    #pragma unroll
    for (int off = 32; off; off >>= 1) { s1 += __shfl_down(s1, off); s2 += __shfl_down(s2, off); }
    const int wid = t >> 6, lane = t & 63;
    if (lane == 0) { rs[wid] = s1; rq[wid] = s2; }
    __syncthreads();
    if (t == 0) {
        const float S1 = rs[0] + rs[1] + rs[2] + rs[3];
        const float S2 = rq[0] + rq[1] + rq[2] + rq[3];
        const float inv = 1.f / (COUT * VV);
        const float mu = S1 * inv;
        const float var = S2 * inv - mu * mu;
        stats[0] = mu;
        stats[1] = rsqrtf(var + 1e-5f);
    }
    __syncthreads();
    const float mu = stats[0], rsd = stats[1];

    const float* gp = gamma + t * VV;
    const float* bp = beta + t * VV;
    const float* xp = x + ((size_t)(n * CIN + t) * LL + m) * VV;
    float* op = out + ((size_t)(n * COUT + t) * LL + m) * VV;
    #pragma unroll
    for (int w = 0; w < VV; ++w) {
        float val = (zw[w] - mu) * rsd * gp[w] + bp[w];
        val = fmaxf(val, 0.f);
        val += xp[w];
        op[w] = fmaxf(val, 0.f);
    }
}

extern "C" void kernel_launch(void* const* d_in, const int* in_sizes, int n_in,
                              void* d_out, int out_size, void* d_ws, size_t ws_size,
                              hipStream_t stream) {
    const float* x      = (const float*)d_in[0];
    const float* A      = (const float*)d_in[1];
    const float* conv_w = (const float*)d_in[2];
    const float* conv_b = (const float*)d_in[3];
    const float* gamma  = (const float*)d_in[4];
    const float* beta   = (const float*)d_in[5];
    const float* ei     = (const float*)d_in[6];
    float* out = (float*)d_out;

    char* ws = (char*)d_ws;
    unsigned short* xa  = (unsigned short*)ws;                    // 184,418,304 B
    unsigned short* z   = (unsigned short*)(ws + 184418304);      //  61,472,768 B
    unsigned short* w2t = (unsigned short*)(ws + 245891072);      //     393,216 B
    float*          b2  = (float*)(ws + 246284288);               //      25,600 B

    k_prep<<<64, 256, 0, stream>>>(A, conv_w, conv_b, ei, w2t, b2, xa);
    k_agg<<<dim3(LL, NN), 256, 0, stream>>>(x, A, ei, xa);
    k_gemm<<<dim3(MBLK, 2), 256, 0, stream>>>(xa, w2t, z);
    k_ln<<<XCDS * NN * MPX, 256, 0, stream>>>(z, x, b2, gamma, beta, out);
}